// Round 11
// baseline (89.597 us; speedup 1.0000x reference)
//
#include <hip/hip_runtime.h>
#include <hip/hip_bf16.h>

// out[e,i] = sum_j (e@W1+b1)[e, i*16+j] * h[e,j]  +  (e@W2+b2)[e,i]
// One fp16 MFMA GEMM over K=576 per 16-edge tile (18x mfma_f32_16x16x32_f16).
// K-mapping (same placement function on A and B sides):
//   main block kk=0..15, slot s=(lane>>4)*8+t:  (d=s, j=kk)
//     A[r,s] = e[edge_r, s] * h[edge_r, kk]     B[s, i=r] = W1[s*256 + r*16 + kk]
//   block 16: A = e[edge, s],                   B = W2[s*16 + r]
//   block 17: s<16: A=h[edge,s], B=b1[r*16+s]; s==16: A=1, B=b2[r]; else 0
//     -> block-17 A is free: hP0-3 (g=0), hP4-7 (g=1), {1,0..} (g=2), 0 (g=3)
// R10 = R9's register diet (packed h, free block-17, Fb depth-2 rotation)
//       + R8's 2-deep staging pipeline (load-to-use ~2 tiles, covers queued
//       HBM latency which R9's 1-deep did not). ~88 VGPR -> 4 waves/SIMD class.
// NO launch_bounds min-waves (R7 spill), NO local arrays (R2 PromoteAlloca).

using f16x8  = __attribute__((ext_vector_type(8))) _Float16;
using f16x2  = __attribute__((ext_vector_type(2))) _Float16;
using fp16v2 = __attribute__((ext_vector_type(2))) __fp16;   // native cvt_pkrtz type
using f32x4  = __attribute__((ext_vector_type(4))) float;
using u32x4  = __attribute__((ext_vector_type(4))) unsigned int;

static __device__ __forceinline__ unsigned int pkrtz(float lo, float hi) {
    fp16v2 p = __builtin_amdgcn_cvt_pkrtz(lo, hi);
    return __builtin_bit_cast(unsigned int, p);
}
static __device__ __forceinline__ f16x2 u2h(unsigned int u) {
    return __builtin_bit_cast(f16x2, u);
}
static __device__ __forceinline__ unsigned int h2u(f16x2 h) {
    return __builtin_bit_cast(unsigned int, h);
}
static __device__ __forceinline__ unsigned short f2h_bits(float x) {
    _Float16 h = (_Float16)x;                 // RNE scalar cast (one-time build only)
    return __builtin_bit_cast(unsigned short, h);
}

__global__ void __launch_bounds__(256) msg_kernel(
    const float* __restrict__ hptr, const float* __restrict__ eptr,
    const float* __restrict__ W1,   const float* __restrict__ b1,
    const float* __restrict__ W2,   const float* __restrict__ b2,
    float* __restrict__ out, int E)
{
    // B fragment store: [kk=0..17][lane=0..63][t=0..7] fp16, 18 KB.
    __shared__ __align__(16) unsigned short Bs[18 * 64 * 8];

    const int lane = threadIdx.x & 63;
    const int g    = lane >> 4;        // K-group (0..3); lane's d-range = [g*8, g*8+8)
    const int r    = lane & 15;        // A row (edge-in-tile) == B/D col (output i)
    const int wv   = threadIdx.x >> 6; // wave id: parallel B-build by t-pair

    // ---- build B in LDS: wave wv handles t = wv*2, wv*2+1 ----
    #pragma unroll
    for (int tq = 0; tq < 2; ++tq) {
        const int t = wv * 2 + tq;
        const int d = g * 8 + t;
        const float4* wp = (const float4*)(W1 + (size_t)d * 256 + r * 16);
        const float4 w0 = wp[0], w1 = wp[1], w2 = wp[2], w3 = wp[3];
        Bs[( 0*64 + lane)*8 + t] = f2h_bits(w0.x);
        Bs[( 1*64 + lane)*8 + t] = f2h_bits(w0.y);
        Bs[( 2*64 + lane)*8 + t] = f2h_bits(w0.z);
        Bs[( 3*64 + lane)*8 + t] = f2h_bits(w0.w);
        Bs[( 4*64 + lane)*8 + t] = f2h_bits(w1.x);
        Bs[( 5*64 + lane)*8 + t] = f2h_bits(w1.y);
        Bs[( 6*64 + lane)*8 + t] = f2h_bits(w1.z);
        Bs[( 7*64 + lane)*8 + t] = f2h_bits(w1.w);
        Bs[( 8*64 + lane)*8 + t] = f2h_bits(w2.x);
        Bs[( 9*64 + lane)*8 + t] = f2h_bits(w2.y);
        Bs[(10*64 + lane)*8 + t] = f2h_bits(w2.z);
        Bs[(11*64 + lane)*8 + t] = f2h_bits(w2.w);
        Bs[(12*64 + lane)*8 + t] = f2h_bits(w3.x);
        Bs[(13*64 + lane)*8 + t] = f2h_bits(w3.y);
        Bs[(14*64 + lane)*8 + t] = f2h_bits(w3.z);
        Bs[(15*64 + lane)*8 + t] = f2h_bits(w3.w);
        Bs[(16*64 + lane)*8 + t] = f2h_bits(W2[d * 16 + r]);
        float v;
        if (d < 16)       v = b1[r * 16 + d];
        else if (d == 16) v = b2[r];
        else              v = 0.0f;
        Bs[(17*64 + lane)*8 + t] = f2h_bits(v);
    }
    __syncthreads();   // only barrier in the kernel

    const int ntiles = (E + 15) >> 4;
    const int nwaves = (gridDim.x * blockDim.x) >> 6;
    const int wid    = (blockIdx.x * blockDim.x + threadIdx.x) >> 6;
    if (wid >= ntiles) return;

    const unsigned short* bsl = &Bs[lane * 8];   // per-lane base; block kk at +kk*512

#define LDSB(KK) __builtin_bit_cast(f16x8, *reinterpret_cast<const u32x4*>(bsl + (KK) * 512))

#define LOADT(T, E0, E1, H0, H1, H2, H3) { \
        int tt = (T); if (tt >= ntiles) tt = ntiles - 1; \
        int cc = tt * 16 + r; if (cc >= E) cc = E - 1; \
        const float4* ep_ = (const float4*)(eptr + (size_t)cc * 32 + g * 8); \
        E0 = ep_[0]; E1 = ep_[1]; \
        const float4* hp_ = (const float4*)(hptr + (size_t)cc * 16); \
        H0 = hp_[0]; H1 = hp_[1]; H2 = hp_[2]; H3 = hp_[3]; }

    // MB: broadcast one fp16 from packed pair (static HALF -> VOP3P op_sel),
    // 4x v_pk_mul_f16, 1 MFMA with rotated B fragment.
#define MB(HPQ, HALF, BF, ACC) { \
        const f16x2 hv_ = u2h(HPQ); \
        const f16x2 hh_ = {hv_[HALF], hv_[HALF]}; \
        u32x4 u_ = {h2u(hh_ * u2h(eP0)), h2u(hh_ * u2h(eP1)), \
                    h2u(hh_ * u2h(eP2)), h2u(hh_ * u2h(eP3))}; \
        ACC = __builtin_amdgcn_mfma_f32_16x16x32_f16( \
            __builtin_bit_cast(f16x8, u_), BF, ACC, 0, 0, 0); }

    // BODY: Fb preload -> convert stage -> prefetch t+2 into stage -> MFMAs -> store
#define BODY(T, E0, E1, H0, H1, H2, H3) { \
        f16x8 Fb0 = LDSB(0), Fb1 = LDSB(1); \
        const unsigned int eP0 = pkrtz(E0.x, E0.y), eP1 = pkrtz(E0.z, E0.w); \
        const unsigned int eP2 = pkrtz(E1.x, E1.y), eP3 = pkrtz(E1.z, E1.w); \
        const unsigned int hP0 = pkrtz(H0.x, H0.y), hP1 = pkrtz(H0.z, H0.w); \
        const unsigned int hP2 = pkrtz(H1.x, H1.y), hP3 = pkrtz(H1.z, H1.w); \
        const unsigned int hP4 = pkrtz(H2.x, H2.y), hP5 = pkrtz(H2.z, H2.w); \
        const unsigned int hP6 = pkrtz(H3.x, H3.y), hP7 = pkrtz(H3.z, H3.w); \
        LOADT((T) + 2 * nwaves, E0, E1, H0, H1, H2, H3); \
        f32x4 acc0 = {0.0f, 0.0f, 0.0f, 0.0f}; \
        f32x4 acc1 = {0.0f, 0.0f, 0.0f, 0.0f}; \
        MB(hP0, 0, Fb0, acc0)  Fb0 = LDSB( 2); \
        MB(hP0, 1, Fb1, acc1)  Fb1 = LDSB( 3); \
        MB(hP1, 0, Fb0, acc0)  Fb0 = LDSB( 4); \
        MB(hP1, 1, Fb1, acc1)  Fb1 = LDSB( 5); \
        MB(hP2, 0, Fb0, acc0)  Fb0 = LDSB( 6); \
        MB(hP2, 1, Fb1, acc1)  Fb1 = LDSB( 7); \
        MB(hP3, 0, Fb0, acc0)  Fb0 = LDSB( 8); \
        MB(hP3, 1, Fb1, acc1)  Fb1 = LDSB( 9); \
        MB(hP4, 0, Fb0, acc0)  Fb0 = LDSB(10); \
        MB(hP4, 1, Fb1, acc1)  Fb1 = LDSB(11); \
        MB(hP5, 0, Fb0, acc0)  Fb0 = LDSB(12); \
        MB(hP5, 1, Fb1, acc1)  Fb1 = LDSB(13); \
        MB(hP6, 0, Fb0, acc0)  Fb0 = LDSB(14); \
        MB(hP6, 1, Fb1, acc1)  Fb1 = LDSB(15); \
        MB(hP7, 0, Fb0, acc0)  Fb0 = LDSB(16); \
        MB(hP7, 1, Fb1, acc1)  Fb1 = LDSB(17); \
        {   u32x4 u_ = {eP0, eP1, eP2, eP3};     /* block 16: A = packed e */ \
            acc0 = __builtin_amdgcn_mfma_f32_16x16x32_f16( \
                __builtin_bit_cast(f16x8, u_), Fb0, acc0, 0, 0, 0); } \
        {   /* block 17: hP0-3 (g=0) / hP4-7 (g=1) / {1,0,..} (g=2) / 0 (g=3) */ \
            const unsigned int a0 = (g == 0) ? hP0 : (g == 1) ? hP4 \
                                   : (g == 2) ? 0x00003C00u : 0u; \
            const unsigned int a1 = (g == 0) ? hP1 : (g == 1) ? hP5 : 0u; \
            const unsigned int a2 = (g == 0) ? hP2 : (g == 1) ? hP6 : 0u; \
            const unsigned int a3 = (g == 0) ? hP3 : (g == 1) ? hP7 : 0u; \
            u32x4 u_ = {a0, a1, a2, a3}; \
            acc1 = __builtin_amdgcn_mfma_f32_16x16x32_f16( \
                __builtin_bit_cast(f16x8, u_), Fb1, acc1, 0, 0, 0); } \
        const int rowbase_ = (T) * 16 + g * 4; \
        float* op_ = out + (size_t)rowbase_ * 16 + r; \
        const float s0_ = acc0[0] + acc1[0], s1_ = acc0[1] + acc1[1]; \
        const float s2_ = acc0[2] + acc1[2], s3_ = acc0[3] + acc1[3]; \
        if (rowbase_ + 3 < E) { op_[0] = s0_; op_[16] = s1_; op_[32] = s2_; op_[48] = s3_; } \
        else { \
            if (rowbase_     < E) op_[ 0] = s0_; \
            if (rowbase_ + 1 < E) op_[16] = s1_; \
            if (rowbase_ + 2 < E) op_[32] = s2_; \
        } }

    // ---- 2-deep pipeline, stages A/B alternate (all names static) ----
    float4 aE0, aE1, aH0, aH1, aH2, aH3;
    float4 bE0, bE1, bH0, bH1, bH2, bH3;

    int t = wid;
    LOADT(t,          aE0, aE1, aH0, aH1, aH2, aH3);
    LOADT(t + nwaves, bE0, bE1, bH0, bH1, bH2, bH3);

    while (true) {
        BODY(t, aE0, aE1, aH0, aH1, aH2, aH3);
        t += nwaves;
        if (t >= ntiles) break;
        BODY(t, bE0, bE1, bH0, bH1, bH2, bH3);
        t += nwaves;
        if (t >= ntiles) break;
    }

#undef BODY
#undef MB
#undef LOADT
#undef LDSB
}

extern "C" void kernel_launch(void* const* d_in, const int* in_sizes, int n_in,
                              void* d_out, int out_size, void* d_ws, size_t ws_size,
                              hipStream_t stream) {
    const float* h  = (const float*)d_in[0];
    const float* e  = (const float*)d_in[1];
    const float* W1 = (const float*)d_in[2];
    const float* b1 = (const float*)d_in[3];
    const float* W2 = (const float*)d_in[4];
    const float* b2 = (const float*)d_in[5];
    float* out = (float*)d_out;

    const int E = in_sizes[0] / 16;   // h is [E,16]

    dim3 grid(2048), block(256);
    hipLaunchKernelGGL(msg_kernel, grid, block, 0, stream,
                       h, e, W1, b1, W2, b2, out, E);
}

// Round 12
// 85.280 us; speedup vs baseline: 1.0506x; 1.0506x over previous
//
#include <hip/hip_runtime.h>
#include <hip/hip_bf16.h>

// out[e,i] = sum_j (e@W1+b1)[e, i*16+j] * h[e,j]  +  (e@W2+b2)[e,i]
// One fp16 MFMA GEMM over K=576 per 16-edge tile (18x mfma_f32_16x16x32_f16).
// K-mapping (same placement function on A and B sides):
//   main block kk=0..15, slot s=(lane>>4)*8+t:  (d=s, j=kk)
//     A[r,s] = e[edge_r, s] * h[edge_r, kk]     B[s, i=r] = W1[s*256 + r*16 + kk]
//   block 16: A = e[edge, s],                   B = W2[s*16 + r]
//   block 17: s<16: A=h[edge,s], B=b1[r*16+s]; s==16: A=1, B=b2[r]; else 0
//     -> block-17 A is free: hP0-3 (g=0), hP4-7 (g=1), {1,0..} (g=2), 0 (g=3)
// R11 = R9 (best: 64 VGPR, 8-wave class, 86.2us) with VMEM ops per tile 6 -> 3:
//   kill the 4x intra-wave h duplication. Lane (g,r) loads ONLY its h quarter
//   h[edge_r, 4g..4g+3], packs to 2 fp16 pairs, and the full 8 packed pairs are
//   rebuilt with 8 ds_bpermute_b32 pulls from the row's 4 lanes (crossbar,
//   conflict-free, on the ~10%-busy DS pipe). -3 loads, -6 pkrtz, -12 VGPR.
// NO launch_bounds min-waves (R7 spill), NO local arrays (R2 PromoteAlloca).

using f16x8  = __attribute__((ext_vector_type(8))) _Float16;
using f16x2  = __attribute__((ext_vector_type(2))) _Float16;
using fp16v2 = __attribute__((ext_vector_type(2))) __fp16;   // native cvt_pkrtz type
using f32x4  = __attribute__((ext_vector_type(4))) float;
using u32x4  = __attribute__((ext_vector_type(4))) unsigned int;

static __device__ __forceinline__ unsigned int pkrtz(float lo, float hi) {
    fp16v2 p = __builtin_amdgcn_cvt_pkrtz(lo, hi);
    return __builtin_bit_cast(unsigned int, p);
}
static __device__ __forceinline__ f16x2 u2h(unsigned int u) {
    return __builtin_bit_cast(f16x2, u);
}
static __device__ __forceinline__ unsigned int h2u(f16x2 h) {
    return __builtin_bit_cast(unsigned int, h);
}
static __device__ __forceinline__ unsigned short f2h_bits(float x) {
    _Float16 h = (_Float16)x;                 // RNE scalar cast (one-time build only)
    return __builtin_bit_cast(unsigned short, h);
}
static __device__ __forceinline__ unsigned int bperm(int baddr, unsigned int src) {
    return (unsigned int)__builtin_amdgcn_ds_bpermute(baddr, (int)src);
}

__global__ void __launch_bounds__(256) msg_kernel(
    const float* __restrict__ hptr, const float* __restrict__ eptr,
    const float* __restrict__ W1,   const float* __restrict__ b1,
    const float* __restrict__ W2,   const float* __restrict__ b2,
    float* __restrict__ out, int E)
{
    // B fragment store: [kk=0..17][lane=0..63][t=0..7] fp16, 18 KB.
    __shared__ __align__(16) unsigned short Bs[18 * 64 * 8];

    const int lane = threadIdx.x & 63;
    const int g    = lane >> 4;        // K-group (0..3); lane's d-range = [g*8, g*8+8)
    const int r    = lane & 15;        // A row (edge-in-tile) == B/D col (output i)
    const int wv   = threadIdx.x >> 6; // wave id: parallel B-build by t-pair

    // ---- build B in LDS: wave wv handles t = wv*2, wv*2+1 ----
    #pragma unroll
    for (int tq = 0; tq < 2; ++tq) {
        const int t = wv * 2 + tq;
        const int d = g * 8 + t;
        const float4* wp = (const float4*)(W1 + (size_t)d * 256 + r * 16);
        const float4 w0 = wp[0], w1 = wp[1], w2 = wp[2], w3 = wp[3];
        Bs[( 0*64 + lane)*8 + t] = f2h_bits(w0.x);
        Bs[( 1*64 + lane)*8 + t] = f2h_bits(w0.y);
        Bs[( 2*64 + lane)*8 + t] = f2h_bits(w0.z);
        Bs[( 3*64 + lane)*8 + t] = f2h_bits(w0.w);
        Bs[( 4*64 + lane)*8 + t] = f2h_bits(w1.x);
        Bs[( 5*64 + lane)*8 + t] = f2h_bits(w1.y);
        Bs[( 6*64 + lane)*8 + t] = f2h_bits(w1.z);
        Bs[( 7*64 + lane)*8 + t] = f2h_bits(w1.w);
        Bs[( 8*64 + lane)*8 + t] = f2h_bits(w2.x);
        Bs[( 9*64 + lane)*8 + t] = f2h_bits(w2.y);
        Bs[(10*64 + lane)*8 + t] = f2h_bits(w2.z);
        Bs[(11*64 + lane)*8 + t] = f2h_bits(w2.w);
        Bs[(12*64 + lane)*8 + t] = f2h_bits(w3.x);
        Bs[(13*64 + lane)*8 + t] = f2h_bits(w3.y);
        Bs[(14*64 + lane)*8 + t] = f2h_bits(w3.z);
        Bs[(15*64 + lane)*8 + t] = f2h_bits(w3.w);
        Bs[(16*64 + lane)*8 + t] = f2h_bits(W2[d * 16 + r]);
        float v;
        if (d < 16)       v = b1[r * 16 + d];
        else if (d == 16) v = b2[r];
        else              v = 0.0f;
        Bs[(17*64 + lane)*8 + t] = f2h_bits(v);
    }
    __syncthreads();   // only barrier in the kernel

    const int ntiles = (E + 15) >> 4;
    const int nwaves = (gridDim.x * blockDim.x) >> 6;
    const int wid    = (blockIdx.x * blockDim.x + threadIdx.x) >> 6;
    if (wid >= ntiles) return;

    const unsigned short* bsl = &Bs[lane * 8];   // per-lane base; block kk at +kk*512

    // bpermute byte-addresses of the 4 lanes holding row r's h quarters
    const int ba0 = (r      ) << 2;    // lane (g'=0, r)
    const int ba1 = (r + 16 ) << 2;    // lane (g'=1, r)
    const int ba2 = (r + 32 ) << 2;    // lane (g'=2, r)
    const int ba3 = (r + 48 ) << 2;    // lane (g'=3, r)

#define LDSB(KK) __builtin_bit_cast(f16x8, *reinterpret_cast<const u32x4*>(bsl + (KK) * 512))

    // 3 loads per tile: e (2x float4, lane's own 8 values), h (1x float4, lane's quarter)
#define LOADT(T, E0, E1, H0) { \
        int tt = (T); if (tt >= ntiles) tt = ntiles - 1; \
        int cc = tt * 16 + r; if (cc >= E) cc = E - 1; \
        const float4* ep_ = (const float4*)(eptr + (size_t)cc * 32 + g * 8); \
        E0 = ep_[0]; E1 = ep_[1]; \
        H0 = *(const float4*)(hptr + (size_t)cc * 16 + g * 4); }

    // MB: broadcast one fp16 from packed pair (static HALF -> VOP3P op_sel),
    // 4x v_pk_mul_f16, 1 MFMA with rotated B fragment.
#define MB(HPQ, HALF, BF, ACC) { \
        const f16x2 hv_ = u2h(HPQ); \
        const f16x2 hh_ = {hv_[HALF], hv_[HALF]}; \
        u32x4 u_ = {h2u(hh_ * u2h(eP0)), h2u(hh_ * u2h(eP1)), \
                    h2u(hh_ * u2h(eP2)), h2u(hh_ * u2h(eP3))}; \
        ACC = __builtin_amdgcn_mfma_f32_16x16x32_f16( \
            __builtin_bit_cast(f16x8, u_), BF, ACC, 0, 0, 0); }

    // ---- 1-stage pipeline (64-VGPR class target) ----
    float4 sE0, sE1, sH;
    int t = wid;
    LOADT(t, sE0, sE1, sH);

    while (true) {
        // B-frag preload (depth-2 rotation)
        f16x8 Fb0 = LDSB(0), Fb1 = LDSB(1);

        // convert staged f32 -> packed fp16 (waits on this tile's loads)
        const unsigned int eP0 = pkrtz(sE0.x, sE0.y), eP1 = pkrtz(sE0.z, sE0.w);
        const unsigned int eP2 = pkrtz(sE1.x, sE1.y), eP3 = pkrtz(sE1.z, sE1.w);
        const unsigned int hQ0 = pkrtz(sH.x, sH.y),   hQ1 = pkrtz(sH.z, sH.w);

        // staging regs consumed -> immediately issue next tile's loads
        LOADT(t + nwaves, sE0, sE1, sH);

        // rebuild full packed h row via crossbar pulls from the row's 4 lanes
        const unsigned int hP0 = bperm(ba0, hQ0), hP1 = bperm(ba0, hQ1);
        const unsigned int hP2 = bperm(ba1, hQ0), hP3 = bperm(ba1, hQ1);
        const unsigned int hP4 = bperm(ba2, hQ0), hP5 = bperm(ba2, hQ1);
        const unsigned int hP6 = bperm(ba3, hQ0), hP7 = bperm(ba3, hQ1);

        f32x4 acc0 = {0.0f, 0.0f, 0.0f, 0.0f};
        f32x4 acc1 = {0.0f, 0.0f, 0.0f, 0.0f};

        MB(hP0, 0, Fb0, acc0)  Fb0 = LDSB( 2);
        MB(hP0, 1, Fb1, acc1)  Fb1 = LDSB( 3);
        MB(hP1, 0, Fb0, acc0)  Fb0 = LDSB( 4);
        MB(hP1, 1, Fb1, acc1)  Fb1 = LDSB( 5);
        MB(hP2, 0, Fb0, acc0)  Fb0 = LDSB( 6);
        MB(hP2, 1, Fb1, acc1)  Fb1 = LDSB( 7);
        MB(hP3, 0, Fb0, acc0)  Fb0 = LDSB( 8);
        MB(hP3, 1, Fb1, acc1)  Fb1 = LDSB( 9);
        MB(hP4, 0, Fb0, acc0)  Fb0 = LDSB(10);
        MB(hP4, 1, Fb1, acc1)  Fb1 = LDSB(11);
        MB(hP5, 0, Fb0, acc0)  Fb0 = LDSB(12);
        MB(hP5, 1, Fb1, acc1)  Fb1 = LDSB(13);
        MB(hP6, 0, Fb0, acc0)  Fb0 = LDSB(14);
        MB(hP6, 1, Fb1, acc1)  Fb1 = LDSB(15);
        MB(hP7, 0, Fb0, acc0)  Fb0 = LDSB(16);
        MB(hP7, 1, Fb1, acc1)  Fb1 = LDSB(17);

        {   // block 16: A = packed e
            u32x4 u_ = {eP0, eP1, eP2, eP3};
            acc0 = __builtin_amdgcn_mfma_f32_16x16x32_f16(
                __builtin_bit_cast(f16x8, u_), Fb0, acc0, 0, 0, 0);
        }
        {   // block 17: A = hP0-3 (g=0) / hP4-7 (g=1) / {1,0,..} (g=2) / 0 (g=3)
            const unsigned int a0 = (g == 0) ? hP0 : (g == 1) ? hP4
                                   : (g == 2) ? 0x00003C00u : 0u;
            const unsigned int a1 = (g == 0) ? hP1 : (g == 1) ? hP5 : 0u;
            const unsigned int a2 = (g == 0) ? hP2 : (g == 1) ? hP6 : 0u;
            const unsigned int a3 = (g == 0) ? hP3 : (g == 1) ? hP7 : 0u;
            u32x4 u_ = {a0, a1, a2, a3};
            acc1 = __builtin_amdgcn_mfma_f32_16x16x32_f16(
                __builtin_bit_cast(f16x8, u_), Fb1, acc1, 0, 0, 0);
        }

        // D: col = r = i, row = g*4 + q = edge-in-tile
        const int rowbase = t * 16 + g * 4;
        float* op = out + (size_t)rowbase * 16 + r;
        const float s0 = acc0[0] + acc1[0], s1 = acc0[1] + acc1[1];
        const float s2 = acc0[2] + acc1[2], s3 = acc0[3] + acc1[3];
        if (rowbase + 3 < E) { op[0] = s0; op[16] = s1; op[32] = s2; op[48] = s3; }
        else {
            if (rowbase     < E) op[ 0] = s0;
            if (rowbase + 1 < E) op[16] = s1;
            if (rowbase + 2 < E) op[32] = s2;
        }

        t += nwaves;
        if (t >= ntiles) break;
    }

#undef MB
#undef LOADT
#undef LDSB
}

extern "C" void kernel_launch(void* const* d_in, const int* in_sizes, int n_in,
                              void* d_out, int out_size, void* d_ws, size_t ws_size,
                              hipStream_t stream) {
    const float* h  = (const float*)d_in[0];
    const float* e  = (const float*)d_in[1];
    const float* W1 = (const float*)d_in[2];
    const float* b1 = (const float*)d_in[3];
    const float* W2 = (const float*)d_in[4];
    const float* b2 = (const float*)d_in[5];
    float* out = (float*)d_out;

    const int E = in_sizes[0] / 16;   // h is [E,16]

    dim3 grid(2048), block(256);
    hipLaunchKernelGGL(msg_kernel, grid, block, 0, stream,
                       h, e, W1, b1, W2, b2, out, E);
}